// Round 8
// baseline (160.251 us; speedup 1.0000x reference)
//
#include <hip/hip_runtime.h>

typedef __attribute__((ext_vector_type(8))) short bfrag;
typedef __attribute__((ext_vector_type(4))) float ffrag;

__device__ __forceinline__ float lrelu(float x) { return x > 0.f ? x : 0.2f * x; }

__device__ __forceinline__ short f2b(float f) {           // fp32 -> bf16 bits, RNE
    union { float f; unsigned u; } x; x.f = f;
    unsigned r = x.u + 0x7fffu + ((x.u >> 16) & 1u);
    return (short)(r >> 16);
}

// ---------------- prep: bf16 decoder weights + transposed conv weights ----------------
__global__ __launch_bounds__(256) void prep_k(
    const float* __restrict__ dw1, const float* __restrict__ dw2, const float* __restrict__ dw3,
    const float* __restrict__ cw1, const float* __restrict__ cw2,
    const float* __restrict__ r1w1, const float* __restrict__ r1w2,
    const float* __restrict__ r2w1, const float* __restrict__ r2w2,
    short* __restrict__ dw1p, short* __restrict__ dw2b, short* __restrict__ dw3b,
    float* __restrict__ wtr)
{
    const int i = blockIdx.x * 256 + threadIdx.x;
    if (i < 65536)  dw2b[i] = f2b(dw2[i]);
    if (i < 200704) dw3b[i] = f2b(dw3[i]);
    if (i < 8192) {
        const int row = i >> 5, k = i & 31;
        dw1p[i] = (k < 16) ? f2b(dw1[row * 16 + k]) : (short)0;
    }
    if (i < 2304) {
        const int co = i & 15;
        const int q  = i >> 4;
        const int k  = q % 9;
        const int ci = q / 9;
        const int src = (co * 16 + ci) * 9 + k;
        wtr[2304 * 1 + i] = cw2 [src];
        wtr[2304 * 2 + i] = r1w1[src];
        wtr[2304 * 3 + i] = r1w2[src];
        wtr[2304 * 4 + i] = r2w1[src];
        wtr[2304 * 5 + i] = r2w2[src];
        if (ci == 0) wtr[i] = cw1[co * 9 + k];
    }
}

// ---------------- fused encoder: 6 convs + VQ (unchanged from round 7) ----------------
template<int CIN, int RIN, int ROUT, int HOUT, bool HASRES, int RRES, int HRES>
__device__ __forceinline__ void conv_stage(
    const float* __restrict__ in, float* __restrict__ out, const float* __restrict__ res,
    const float* __restrict__ wt, const float* __restrict__ bias, int r0, int t)
{
    const int lo = (r0 - HOUT > 0) ? r0 - HOUT : 0;
    const int hi = (r0 + 8 + HOUT < 32) ? r0 + 8 + HOUT : 32;
    const int base = r0 - HOUT;
    const int nlow = lo - base;
    const int hih  = hi - base;
    if (nlow > 0 || hih < ROUT) {
        const int nz = (nlow + (ROUT - hih)) * 36;
        for (int i = t; i < 16 * nz; i += 512) {
            const int ch = i / nz, rem = i % nz;
            int r = rem / 36; const int c = rem % 36;
            r = (r < nlow) ? r : (hih + (r - nlow));
            out[(ch * ROUT + r) * 36 + c] = 0.f;
        }
    }
    for (int i = t; i < 16 * ROUT * 2; i += 512) {
        const int ch = i / (ROUT * 2), rem = i % (ROUT * 2);
        out[(ch * ROUT + (rem >> 1)) * 36 + ((rem & 1) ? 33 : 0)] = 0.f;
    }

    const int n = (hi - lo) * 32;
    for (int u = t; u < n; u += 512) {
        const int row = lo + (u >> 5), col = u & 31;
        const int prin = row - r0 + HOUT;
        float acc[16];
        #pragma unroll
        for (int co = 0; co < 16; ++co) acc[co] = bias[co];
        for (int ci = 0; ci < CIN; ++ci) {
            const float* ip = in + (ci * RIN + prin) * 36 + col;
            float v[9];
            #pragma unroll
            for (int kh = 0; kh < 3; ++kh)
                #pragma unroll
                for (int kw = 0; kw < 3; ++kw) v[kh * 3 + kw] = ip[kh * 36 + kw];
            const float* wp = wt + ci * 144;
            #pragma unroll
            for (int k = 0; k < 9; ++k)
                #pragma unroll
                for (int co = 0; co < 16; ++co)
                    acc[co] = fmaf(v[k], wp[k * 16 + co], acc[co]);
        }
        const int pro = row - base;
        #pragma unroll
        for (int co = 0; co < 16; ++co) {
            float val = lrelu(acc[co]);
            if (HASRES) val += res[(co * RRES + (row - (r0 - HRES))) * 36 + col + 1];
            out[(co * ROUT + pro) * 36 + col + 1] = val;
        }
    }
    __syncthreads();
}

__global__ __launch_bounds__(512, 1) void enc_k(
    const float* __restrict__ x, const float* __restrict__ wtr,
    const float* __restrict__ cb1, const float* __restrict__ cb2,
    const float* __restrict__ r1b1, const float* __restrict__ r1b2,
    const float* __restrict__ r2b1, const float* __restrict__ r2b2,
    const float* __restrict__ cbk,
    float* __restrict__ ze, float* __restrict__ zq,
    float* __restrict__ zst, short* __restrict__ zstb)
{
    __shared__ float xb[20 * 36];
    __shared__ float Abuf[16 * 18 * 36];
    __shared__ float Bbuf[16 * 16 * 36];
    __shared__ float Cbuf[16 * 12 * 36];
    __shared__ float scb[160];
    __shared__ int   sbest[256];

    const int t  = threadIdx.x;
    const int b  = blockIdx.x >> 2;
    const int r0 = (blockIdx.x & 3) * 8;

    if (t < 160) scb[t] = cbk[t];
    for (int i = t; i < 720; i += 512) {
        const int r = i / 36, c = i % 36;
        const int rl = r0 - 6 + r, cl = c - 1;
        xb[i] = (rl >= 0 && rl < 32 && cl >= 0 && cl < 32)
              ? x[(size_t)b * 1024 + rl * 32 + cl] : 0.f;
    }
    __syncthreads();

    conv_stage<1,  20, 18, 5, false,  1, 0>(xb,   Abuf, nullptr, wtr,          cb1,  r0, t);
    conv_stage<16, 18, 16, 4, false,  1, 0>(Abuf, Bbuf, nullptr, wtr + 2304,   cb2,  r0, t);
    conv_stage<16, 16, 14, 3, false,  1, 0>(Bbuf, Abuf, nullptr, wtr + 4608,   r1b1, r0, t);
    conv_stage<16, 14, 12, 2, true,  16, 4>(Abuf, Cbuf, Bbuf,    wtr + 6912,   r1b2, r0, t);
    conv_stage<16, 12, 10, 1, false,  1, 0>(Cbuf, Abuf, nullptr, wtr + 9216,   r2b1, r0, t);
    conv_stage<16, 10,  8, 0, true,  12, 2>(Abuf, Bbuf, Cbuf,    wtr + 11520,  r2b2, r0, t);

    const size_t obase = (size_t)b * 16384 + r0 * 32;
    for (int i = t; i < 4096; i += 512) {
        const int c = i >> 8, px = i & 255;
        ze[obase + c * 1024 + px] = Bbuf[(c * 8 + (px >> 5)) * 36 + (px & 31) + 1];
    }
    if (t < 256) {
        const int r = t >> 5, col = t & 31;
        float xv[16]; float xx = 0.f;
        #pragma unroll
        for (int c = 0; c < 16; ++c) { xv[c] = Bbuf[(c * 8 + r) * 36 + col + 1]; xx += xv[c] * xv[c]; }
        int best = 0; float bestd = 1e30f;
        #pragma unroll
        for (int k = 0; k < 10; ++k) {
            float dot = 0.f, cn = 0.f;
            #pragma unroll
            for (int c = 0; c < 16; ++c) { const float cv = scb[k * 16 + c]; dot += xv[c] * cv; cn += cv * cv; }
            const float d2 = xx + cn - 2.f * dot;
            if (d2 < bestd) { bestd = d2; best = k; }
        }
        sbest[t] = best;
        unsigned pk[8];
        #pragma unroll
        for (int c = 0; c < 16; ++c) {
            const float q = scb[best * 16 + c];
            const float s = q + (xv[c] - q);
            const unsigned hb = (unsigned)(unsigned short)f2b(s);
            if (c & 1) pk[c >> 1] |= hb << 16; else pk[c >> 1] = hb;
        }
        const size_t n = (size_t)b * 1024 + (size_t)(r0 + r) * 32 + col;
        uint4* d = (uint4*)(zstb + n * 16);
        d[0] = make_uint4(pk[0], pk[1], pk[2], pk[3]);
        d[1] = make_uint4(pk[4], pk[5], pk[6], pk[7]);
    }
    __syncthreads();
    for (int i = t; i < 4096; i += 512) {
        const int c = i >> 8, px = i & 255;
        const float q  = scb[sbest[px] * 16 + c];
        const float xv = Bbuf[(c * 8 + (px >> 5)) * 36 + (px & 31) + 1];
        zq[obase + c * 1024 + px]  = q;
        zst[obase + c * 1024 + px] = q + (xv - q);
    }
}

// ---------------- fused MFMA decoder v3: 8 waves/block, 256 px, ring-3 panel pipeline ------
// Counted vmcnt(1) + raw s_barrier keeps 2 panels in flight (T3/T4). Biases in LDS.
// Per-wave g [32][256] bf16 swizzled; unified 65-panel loop (16 x dw2b, 49 x dw3b).
__global__ __launch_bounds__(512, 1) void decoder_k(
    const short* __restrict__ zstb,
    const short* __restrict__ dw1p, const float* __restrict__ db1,
    const short* __restrict__ dw2b, const float* __restrict__ db2,
    const short* __restrict__ dw3b, const float* __restrict__ db3,
    float* __restrict__ xrec)
{
    __shared__ __align__(16) short g[8 * 8192];      // 128 KB: per-wave [32][256] bf16
    __shared__ __align__(16) short pan[3][4096];     // 24 KB: 8KB panel ring
    __shared__ float sb[1040];                       // db2(256) ++ db3(784)

    const int t    = threadIdx.x;
    const int lane = t & 63;
    const int wid  = t >> 6;
    const int lr   = lane & 15;
    const int lg   = lane >> 4;
    const int row0 = blockIdx.x * 256 + wid * 32;
    short* gw = g + wid * 8192;

    #define GB(row, kbyte) (((row) * 512 + (kbyte)) ^ (((row) & 7) << 4))

    auto stage = [&](short* dst, const short* src) {    // 8KB panel, 1x16B per thread
        const int L = t * 16;
        const int S = L ^ (((L >> 9) & 7) << 4);        // inverse-swizzled source
        __builtin_amdgcn_global_load_lds(
            (const __attribute__((address_space(1))) void*)((const char*)src + S),
            (__attribute__((address_space(3))) void*)((char*)dst + L), 16, 0, 0);
    };

    stage(&pan[0][0], dw2b);                     // panels 0,1 in flight during L1
    stage(&pan[1][0], dw2b + 4096);

    for (int i = t; i < 1040; i += 512) sb[i] = (i < 256) ? db2[i] : db3[i - 256];

    // ---- L1: A1 from global (K=16 padded), write g1 (wave-private, swizzled) ----
    {
        bfrag A1[2];
        #pragma unroll
        for (int rt = 0; rt < 2; ++rt) {
            bfrag z;
            #pragma unroll
            for (int i = 0; i < 8; ++i) z[i] = 0;
            if (lg < 2)
                z = *(const bfrag*)&zstb[(size_t)(row0 + rt * 16 + lr) * 16 + lg * 8];
            A1[rt] = z;
        }
        #pragma unroll
        for (int ct = 0; ct < 16; ++ct) {
            const int col = ct * 16 + lr;
            const bfrag B = *(const bfrag*)&dw1p[col * 32 + lg * 8];
            const float bv = db1[col];
            ffrag acc[2];
            #pragma unroll
            for (int rt = 0; rt < 2; ++rt) {
                #pragma unroll
                for (int q = 0; q < 4; ++q) acc[rt][q] = bv;
                acc[rt] = __builtin_amdgcn_mfma_f32_16x16x32_bf16(A1[rt], B, acc[rt], 0, 0, 0);
            }
            #pragma unroll
            for (int rt = 0; rt < 2; ++rt)
                #pragma unroll
                for (int q = 0; q < 4; ++q) {
                    const int R = rt * 16 + lg * 4 + q;
                    *(short*)((char*)gw + GB(R, col * 2)) = f2b(lrelu(acc[rt][q]));
                }
        }
    }

    // ---- A (K=256) from g1 into regs ----
    bfrag A[2][8];
    #pragma unroll
    for (int rt = 0; rt < 2; ++rt)
        #pragma unroll
        for (int kk = 0; kk < 8; ++kk)
            A[rt][kk] = *(const bfrag*)((char*)gw + GB(rt * 16 + lr, kk * 64 + lg * 16));

    __syncthreads();   // full drain once: panels 0,1 + sb visible to all

    float* slab = (float*)gw;                    // [32][36] fp32 overlay (L3 region)

    // ---- unified panel loop: p 0..15 = L2 (dw2b), 16..64 = L3 (dw3b) ----
    #pragma unroll 1
    for (int p = 0; p < 65; ++p) {
        if (p) {                                  // p==0: syncthreads above already synced
            asm volatile("s_waitcnt vmcnt(1)" ::: "memory");   // panel p resident
            __builtin_amdgcn_s_barrier();
            __builtin_amdgcn_sched_barrier(0);
        }
        if (p == 16) {                            // g2 complete -> reload A, free g for slab
            #pragma unroll
            for (int rt = 0; rt < 2; ++rt)
                #pragma unroll
                for (int kk = 0; kk < 8; ++kk)
                    A[rt][kk] = *(const bfrag*)((char*)gw + GB(rt * 16 + lr, kk * 64 + lg * 16));
        }
        if (p + 2 <= 64) {                        // keep 2 panels in flight
            const int p2 = p + 2;
            stage(&pan[p2 % 3][0], (p2 < 16) ? dw2b + p2 * 4096
                                             : dw3b + (size_t)(p2 - 16) * 4096);
        }

        const char* bp = (const char*)&pan[p % 3][0];
        bfrag Bf[8];
        #pragma unroll
        for (int kk = 0; kk < 8; ++kk)
            Bf[kk] = *(const bfrag*)(bp + ((lr * 512 + kk * 64 + lg * 16) ^ ((lr & 7) << 4)));

        ffrag aE[2], aO[2];
        const float bv = sb[p * 16 + lr];         // db2[col] / db3[col] via LDS
        #pragma unroll
        for (int rt = 0; rt < 2; ++rt)
            #pragma unroll
            for (int q = 0; q < 4; ++q) { aE[rt][q] = bv; aO[rt][q] = 0.f; }
        #pragma unroll
        for (int kk = 0; kk < 8; kk += 2)
            #pragma unroll
            for (int rt = 0; rt < 2; ++rt) {
                aE[rt] = __builtin_amdgcn_mfma_f32_16x16x32_bf16(A[rt][kk],     Bf[kk],     aE[rt], 0, 0, 0);
                aO[rt] = __builtin_amdgcn_mfma_f32_16x16x32_bf16(A[rt][kk + 1], Bf[kk + 1], aO[rt], 0, 0, 0);
            }

        if (p < 16) {                             // L2 epilogue: lrelu -> g2 in place
            const int col = p * 16 + lr;
            #pragma unroll
            for (int rt = 0; rt < 2; ++rt)
                #pragma unroll
                for (int q = 0; q < 4; ++q) {
                    const int R = rt * 16 + lg * 4 + q;
                    *(short*)((char*)gw + GB(R, col * 2)) = f2b(lrelu(aE[rt][q] + aO[rt][q]));
                }
        } else {                                  // L3 epilogue: sigmoid -> slab -> xrec
            const int q3 = p - 16;
            const int ph = q3 & 1;
            #pragma unroll
            for (int rt = 0; rt < 2; ++rt)
                #pragma unroll
                for (int q = 0; q < 4; ++q) {
                    const int R = rt * 16 + lg * 4 + q;
                    const float v = aE[rt][q] + aO[rt][q];
                    slab[R * 36 + ph * 16 + lr] = 1.f / (1.f + __expf(-v));
                }
            if (ph) {                             // pair (q3-1,q3): 32 cols, 128B runs
                const int cb = (q3 - 1) * 16;
                #pragma unroll
                for (int f0 = 0; f0 < 4; ++f0) {
                    const int f = f0 * 64 + lane;
                    const int row = f >> 3, c4 = f & 7;
                    const float4 v = *(const float4*)&slab[row * 36 + c4 * 4];
                    *(float4*)&xrec[(size_t)(row0 + row) * 784 + cb + c4 * 4] = v;
                }
            }
            if (q3 == 48) {                       // tail tile: cols 768..783
                #pragma unroll
                for (int f0 = 0; f0 < 2; ++f0) {
                    const int f = f0 * 64 + lane;
                    const int row = f >> 2, c4 = f & 3;
                    const float4 v = *(const float4*)&slab[row * 36 + c4 * 4];
                    *(float4*)&xrec[(size_t)(row0 + row) * 784 + 768 + c4 * 4] = v;
                }
            }
        }
    }
    #undef GB
}

extern "C" void kernel_launch(void* const* d_in, const int* in_sizes, int n_in,
                              void* d_out, int out_size, void* d_ws, size_t ws_size,
                              hipStream_t stream) {
    const float* x    = (const float*)d_in[0];
    const float* cw1  = (const float*)d_in[1];
    const float* cb1  = (const float*)d_in[2];
    const float* cw2  = (const float*)d_in[3];
    const float* cb2  = (const float*)d_in[4];
    const float* r1w1 = (const float*)d_in[5];
    const float* r1b1 = (const float*)d_in[6];
    const float* r1w2 = (const float*)d_in[7];
    const float* r1b2 = (const float*)d_in[8];
    const float* r2w1 = (const float*)d_in[9];
    const float* r2b1 = (const float*)d_in[10];
    const float* r2w2 = (const float*)d_in[11];
    const float* r2b2 = (const float*)d_in[12];
    const float* cbk  = (const float*)d_in[13];
    const float* dw1  = (const float*)d_in[14];
    const float* db1  = (const float*)d_in[15];
    const float* dw2  = (const float*)d_in[16];
    const float* db2  = (const float*)d_in[17];
    const float* dw3  = (const float*)d_in[18];
    const float* db3  = (const float*)d_in[19];

    float* out  = (float*)d_out;
    float* xrec = out;                                   // [65536, 784]
    float* ze   = out + 51380224;                        // [64,16,32,32]
    float* zst  = ze + 1048576;
    float* zq   = zst + 1048576;

    short* zstb = (short*)d_ws;                          // [65536][16] bf16
    short* dw2b = zstb + 1048576;
    short* dw3b = dw2b + 65536;
    short* dw1p = dw3b + 200704;                         // [256][32] zero-padded
    float* wtr  = (float*)(dw1p + 8192);                 // [6][2304] transposed conv w

    prep_k<<<784, 256, 0, stream>>>(dw1, dw2, dw3, cw1, cw2, r1w1, r1w2, r2w1, r2w2,
                                    dw1p, dw2b, dw3b, wtr);

    enc_k<<<256, 512, 0, stream>>>(x, wtr, cb1, cb2, r1b1, r1b2, r2b1, r2b2,
                                   cbk, ze, zq, zst, zstb);

    decoder_k<<<256, 512, 0, stream>>>(zstb, dw1p, db1, dw2b, db2, dw3b, db3, xrec);
}